// Round 1
// baseline (412.955 us; speedup 1.0000x reference)
//
#include <hip/hip_runtime.h>
#include <hip/hip_bf16.h>
#include <math.h>

#define B_ 2
#define N_ 4096
#define C_ 256
#define H_ 8
#define K_ 32
#define NP_ (B_*N_)

typedef __attribute__((ext_vector_type(8))) short bf16x8;
typedef __attribute__((ext_vector_type(4))) float f32x4;
typedef __attribute__((ext_vector_type(4))) unsigned short ushort4_t;

__device__ __forceinline__ float bf2f(unsigned short v){
    union { unsigned int u; float f; } x; x.u = ((unsigned int)v) << 16; return x.f;
}
__device__ __forceinline__ unsigned short f2bf(float f){
    union { float f; unsigned int u; } x; x.f = f;
    return (unsigned short)((x.u + 0x7FFFu + ((x.u >> 16) & 1u)) >> 16);
}

// ---------------- weight fp32 -> bf16 ----------------
__global__ void k_f2bf(const float* __restrict__ src, unsigned short* __restrict__ dst, int n){
    int i = blockIdx.x*256 + threadIdx.x;
    if (i < n) dst[i] = f2bf(src[i]);
}

// ---------------- LN stats over C for featA (B,C,N) ----------------
__global__ __launch_bounds__(256) void k_ln_stats(const float* __restrict__ fa, float* __restrict__ stats){
    __shared__ float part[2][4][64];
    const int lane = threadIdx.x & 63, wq = threadIdx.x >> 6;
    const int pbase = blockIdx.x * 64;          // 128 blocks x 64 points
    const int p = pbase + lane;
    const int b = p >> 12, n = p & 4095;
    const float* base = fa + (size_t)b*C_*N_ + n;
    float s = 0.f, sq = 0.f;
    #pragma unroll 8
    for (int i = 0; i < 64; i++){
        float x = base[(size_t)(wq*64 + i)*N_];
        s += x; sq = fmaf(x, x, sq);
    }
    part[0][wq][lane] = s; part[1][wq][lane] = sq;
    __syncthreads();
    if (threadIdx.x < 64){
        int l = threadIdx.x;
        float S = part[0][0][l]+part[0][1][l]+part[0][2][l]+part[0][3][l];
        float Q = part[1][0][l]+part[1][1][l]+part[1][2][l]+part[1][3][l];
        float m = S*(1.f/256.f);
        float var = Q*(1.f/256.f) - m*m;
        stats[2*(pbase+l)]   = m;
        stats[2*(pbase+l)+1] = rsqrtf(var + 1e-5f);
    }
}

// ---------------- transpose (B,C,N)->(B,N,C) bf16, optional LN ----------------
template<int DO_LN>
__global__ __launch_bounds__(256) void k_transpose(const float* __restrict__ src,
                            unsigned short* __restrict__ dst, int dstStride,
                            const float* __restrict__ stats,
                            const float* __restrict__ lnw, const float* __restrict__ lnb){
    __shared__ float tile[64][65];
    const int b = blockIdx.z;
    const int n0 = blockIdx.x*64, c0 = blockIdx.y*64;
    const int tx = threadIdx.x & 63, ty = threadIdx.x >> 6;
    const float* sp = src + (size_t)b*C_*N_;
    #pragma unroll
    for (int i = 0; i < 16; i++){
        int cr = ty + i*4;
        tile[cr][tx] = sp[(size_t)(c0+cr)*N_ + n0 + tx];
    }
    __syncthreads();
    const int c = c0 + tx;
    #pragma unroll
    for (int i = 0; i < 16; i++){
        int nr = ty + i*4;
        int n = n0 + nr;
        float x = tile[tx][nr];
        int p = (b<<12) + n;
        if (DO_LN){
            float mean = stats[2*p], rstd = stats[2*p+1];
            x = (x - mean)*rstd*lnw[c] + lnb[c];
        }
        dst[(size_t)p*dstStride + c] = f2bf(x);
    }
}

// ---------------- KNN: 32 smallest d2 per point ----------------
__global__ __launch_bounds__(256) void k_knn(const float* __restrict__ xyzA, const float* __restrict__ xyzB,
                      int* __restrict__ knn){
    const int p = blockIdx.x;
    const int b = p >> 12;
    const int tid = threadIdx.x;
    const float* pa = xyzA + (size_t)p*3;
    const float ax = pa[0], ay = pa[1], az = pa[2];
    const float sa = ax*ax + ay*ay + az*az;
    const float* pb = xyzB + (size_t)b*N_*3;
    unsigned long long key[16];
    #pragma unroll
    for (int i = 0; i < 16; i++){
        int m = tid + i*256;
        float bx = pb[m*3], by = pb[m*3+1], bz = pb[m*3+2];
        float sb = bx*bx + by*by + bz*bz;
        float dot = ax*bx + ay*by + az*bz;
        float d2 = (sa + sb) - 2.f*dot;
        union { float f; unsigned int u; } cv; cv.f = d2;
        unsigned int u = cv.u ^ (0x80000000u | (unsigned int)((int)cv.u >> 31));
        key[i] = (((unsigned long long)u) << 12) | (unsigned int)m;
    }
    __shared__ unsigned long long red[4];
    for (int it = 0; it < K_; it++){
        unsigned long long kmin = ~0ull;
        #pragma unroll
        for (int i = 0; i < 16; i++){ unsigned long long kk = key[i]; kmin = kk < kmin ? kk : kmin; }
        #pragma unroll
        for (int off = 1; off < 64; off <<= 1){
            unsigned long long o = __shfl_xor(kmin, off, 64);
            kmin = o < kmin ? o : kmin;
        }
        if ((tid & 63) == 0) red[tid >> 6] = kmin;
        __syncthreads();
        unsigned long long a0 = red[0] < red[1] ? red[0] : red[1];
        unsigned long long a1 = red[2] < red[3] ? red[2] : red[3];
        unsigned long long k0 = a0 < a1 ? a0 : a1;
        int m = (int)(k0 & 0xFFFull);
        if (tid == 0) knn[(size_t)p*K_ + it] = m;
        if ((m & 255) == tid){
            int s = m >> 8;
            #pragma unroll
            for (int i = 0; i < 16; i++) if (i == s) key[i] = ~0ull;
        }
        __syncthreads();
    }
}

// ---------------- generic MFMA GEMM: Y = epilogue(X(M,Kin) * W(O,Kin)^T) ----------------
// MODE 0: +bias -> bf16 Y (ld ldy)
// MODE 1: *scale(bn)+shift, relu -> bf16 Y
// MODE 2: +bias + residual featA, write fp32 out transposed (B,C,N)
template<int MODE>
__global__ __launch_bounds__(256) void k_gemm(
    const unsigned short* __restrict__ X, int ldx,
    const unsigned short* __restrict__ W, int Kin,
    const float* __restrict__ e0, const float* __restrict__ e1,
    unsigned short* __restrict__ Y, int ldy,
    const float* __restrict__ resid, float* __restrict__ out)
{
    const int wid = threadIdx.x >> 6, lane = threadIdx.x & 63;
    const int lr = lane & 15, lg = lane >> 4;
    const int mw = blockIdx.x * 128 + wid * 32;
    const int cn = blockIdx.y * 64;
    f32x4 acc[2][4] = {};
    const unsigned short* xr0 = X + (size_t)(mw + lr) * ldx;
    const unsigned short* xr1 = xr0 + (size_t)16 * ldx;
    const unsigned short* wr0 = W + (size_t)(cn + lr) * Kin;
    for (int k0 = 0; k0 < Kin; k0 += 32){
        const int k = k0 + lg*8;
        bf16x8 a0 = *(const bf16x8*)(xr0 + k);
        bf16x8 a1 = *(const bf16x8*)(xr1 + k);
        #pragma unroll
        for (int ni = 0; ni < 4; ni++){
            bf16x8 bf = *(const bf16x8*)(wr0 + (size_t)ni*16*Kin + k);
            acc[0][ni] = __builtin_amdgcn_mfma_f32_16x16x32_bf16(a0, bf, acc[0][ni], 0, 0, 0);
            acc[1][ni] = __builtin_amdgcn_mfma_f32_16x16x32_bf16(a1, bf, acc[1][ni], 0, 0, 0);
        }
    }
    #pragma unroll
    for (int mi = 0; mi < 2; mi++){
        const int pbase = mw + mi*16 + lg*4;
        #pragma unroll
        for (int ni = 0; ni < 4; ni++){
            const int o = cn + ni*16 + lr;
            if (MODE == 0){
                float bias = e0[o];
                #pragma unroll
                for (int r = 0; r < 4; r++)
                    Y[(size_t)(pbase + r)*ldy + o] = f2bf(acc[mi][ni][r] + bias);
            } else if (MODE == 1){
                float sc = e0[o] * 0.9999950000374997f;   // rsqrt(1+1e-5)*bn_g
                float sh = e1[o];
                #pragma unroll
                for (int r = 0; r < 4; r++){
                    float vv = fmaf(acc[mi][ni][r], sc, sh);
                    Y[(size_t)(pbase + r)*ldy + o] = f2bf(fmaxf(vv, 0.f));
                }
            } else {
                float bias = e0[o];
                const int b = pbase >> 12, nn = pbase & 4095;
                const size_t adr = ((size_t)b*C_ + o)*N_ + nn;
                f32x4 rv = *(const f32x4*)(resid + adr);
                f32x4 ov;
                #pragma unroll
                for (int r = 0; r < 4; r++) ov[r] = acc[mi][ni][r] + bias + rv[r];
                *(f32x4*)(out + adr) = ov;
            }
        }
    }
}

// ---------------- dual-path neighbor attention, one wave per point ----------------
__global__ __launch_bounds__(256) void k_attn(
    const unsigned short* __restrict__ QS, const unsigned short* __restrict__ KS,
    const unsigned short* __restrict__ VV,
    const unsigned short* __restrict__ QD, const unsigned short* __restrict__ KD,
    const int* __restrict__ KNN,
    const float* __restrict__ lnsw, const float* __restrict__ lnsb,
    const float* __restrict__ lndw, const float* __restrict__ lndb,
    unsigned short* __restrict__ F)
{
    __shared__ float qs_l[4][256], qd_l[4][256];
    __shared__ float ws_l[4][8][32], wd_l[4][8][32];
    __shared__ int idx_l[4][32];
    const int wid = threadIdx.x >> 6, lane = threadIdx.x & 63;
    const int p = blockIdx.x*4 + wid;
    const int b = p >> 12;
    {
        ushort4_t qv = *(const ushort4_t*)(QS + (size_t)p*256 + lane*4);
        ushort4_t dv = *(const ushort4_t*)(QD + (size_t)p*256 + lane*4);
        #pragma unroll
        for (int j = 0; j < 4; j++){
            qs_l[wid][lane*4+j] = bf2f(qv[j]);
            qd_l[wid][lane*4+j] = bf2f(dv[j]);
        }
        if (lane < 32) idx_l[wid][lane] = KNN[(size_t)p*K_ + lane];
    }
    __syncthreads();
    const int kk = lane & 31, hg = lane >> 5;
    {
        const int nbr = idx_l[wid][kk];
        const unsigned short* krow = KS + ((size_t)(b<<12) + nbr)*256;
        const unsigned short* drow = KD + ((size_t)(b<<12) + nbr)*256;
        #pragma unroll
        for (int j = 0; j < 4; j++){
            const int h = hg*4 + j;
            const float* qs_h = &qs_l[wid][h*32];
            const float* qd_h = &qd_l[wid][h*32];
            const bf16x8* kr = (const bf16x8*)(krow + h*32);
            const bf16x8* dr = (const bf16x8*)(drow + h*32);
            float s = 0.f, dd = 0.f;
            #pragma unroll
            for (int c8 = 0; c8 < 4; c8++){
                bf16x8 kv = kr[c8], dvv = dr[c8];
                #pragma unroll
                for (int e = 0; e < 8; e++){
                    int d = c8*8 + e;
                    s = fmaf(qs_h[d], bf2f((unsigned short)kv[e]), s);
                    float df = qd_h[d] - bf2f((unsigned short)dvv[e]);
                    dd = fmaf(df, df, dd);
                }
            }
            float sim = s * 0.17677669529663687f;   // 1/sqrt(32)
            float dist = sqrtf(dd);
            float m1 = sim, m2 = dist;
            #pragma unroll
            for (int off = 1; off < 32; off <<= 1){
                m1 = fmaxf(m1, __shfl_xor(m1, off, 64));
                m2 = fmaxf(m2, __shfl_xor(m2, off, 64));
            }
            float e1v = __expf(sim - m1);
            float e2v = __expf(dist - m2);
            float s1 = e1v, s2 = e2v;
            #pragma unroll
            for (int off = 1; off < 32; off <<= 1){
                s1 += __shfl_xor(s1, off, 64);
                s2 += __shfl_xor(s2, off, 64);
            }
            ws_l[wid][h][kk] = e1v / s1;
            wd_l[wid][h][kk] = e2v / s2;
        }
    }
    __syncthreads();
    const int d = kk;
    float cs[4] = {0,0,0,0}, cd[4] = {0,0,0,0};
    for (int t = 0; t < 32; t++){
        const int nbr = idx_l[wid][t];
        const unsigned short* vrow = VV + ((size_t)(b<<12) + nbr)*256;
        #pragma unroll
        for (int j = 0; j < 4; j++){
            const int h = hg*4 + j;
            float vf = bf2f(vrow[h*32 + d]);
            cs[j] = fmaf(ws_l[wid][h][t], vf, cs[j]);
            cd[j] = fmaf(wd_l[wid][h][t], vf, cd[j]);
        }
    }
    float s1 = 0.f, q1 = 0.f, s2 = 0.f, q2 = 0.f;
    #pragma unroll
    for (int j = 0; j < 4; j++){
        s1 += cs[j]; q1 = fmaf(cs[j], cs[j], q1);
        s2 += cd[j]; q2 = fmaf(cd[j], cd[j], q2);
    }
    #pragma unroll
    for (int off = 1; off < 64; off <<= 1){
        s1 += __shfl_xor(s1, off, 64); q1 += __shfl_xor(q1, off, 64);
        s2 += __shfl_xor(s2, off, 64); q2 += __shfl_xor(q2, off, 64);
    }
    float m1 = s1*(1.f/256.f), m2 = s2*(1.f/256.f);
    float r1 = rsqrtf(q1*(1.f/256.f) - m1*m1 + 1e-5f);
    float r2 = rsqrtf(q2*(1.f/256.f) - m2*m2 + 1e-5f);
    unsigned short* frow = F + (size_t)p*768;
    #pragma unroll
    for (int j = 0; j < 4; j++){
        int c = (hg*4 + j)*32 + d;
        frow[256 + c] = f2bf((cs[j]-m1)*r1*lnsw[c] + lnsb[c]);
        frow[512 + c] = f2bf((cd[j]-m2)*r2*lndw[c] + lndb[c]);
    }
}

extern "C" void kernel_launch(void* const* d_in, const int* in_sizes, int n_in,
                              void* d_out, int out_size, void* d_ws, size_t ws_size,
                              hipStream_t stream)
{
    const float* xyzA   = (const float*)d_in[0];
    const float* xyzB   = (const float*)d_in[1];
    const float* featA  = (const float*)d_in[2];
    const float* featB  = (const float*)d_in[3];
    const float* ln_in_w= (const float*)d_in[4];
    const float* ln_in_b= (const float*)d_in[5];
    const float* wq  = (const float*)d_in[6];
    const float* bq  = (const float*)d_in[7];
    const float* wk  = (const float*)d_in[8];
    const float* bk  = (const float*)d_in[9];
    const float* wv  = (const float*)d_in[10];
    const float* bv  = (const float*)d_in[11];
    const float* wqd = (const float*)d_in[12];
    const float* bqd = (const float*)d_in[13];
    const float* wkd = (const float*)d_in[14];
    const float* bkd = (const float*)d_in[15];
    const float* lnsw = (const float*)d_in[16];
    const float* lnsb = (const float*)d_in[17];
    const float* lndw = (const float*)d_in[18];
    const float* lndb = (const float*)d_in[19];
    const float* fw1 = (const float*)d_in[20];
    const float* bng = (const float*)d_in[21];
    const float* bnb = (const float*)d_in[22];
    const float* fw2 = (const float*)d_in[23];
    const float* fb2 = (const float*)d_in[24];
    float* out = (float*)d_out;
    char* ws = (char*)d_ws;

    unsigned short* F    = (unsigned short*)(ws + 0);          // 8192*768 bf16
    unsigned short* XBT  = (unsigned short*)(ws + 12582912);   // 8192*256
    unsigned short* QSb  = (unsigned short*)(ws + 16777216);
    unsigned short* KSb  = (unsigned short*)(ws + 20971520);
    unsigned short* VVb  = (unsigned short*)(ws + 25165824);
    unsigned short* QDb  = (unsigned short*)(ws + 29360128);
    unsigned short* KDb  = (unsigned short*)(ws + 33554432);
    unsigned short* Y1   = (unsigned short*)(ws + 37748736);   // 8192*512
    int*            KNNi = (int*)(ws + 46137344);              // 8192*32
    float*          STATS= (float*)(ws + 47185920);            // 8192*2
    unsigned short* WQb  = (unsigned short*)(ws + 47251456);
    unsigned short* WKb  = (unsigned short*)(ws + 47382528);
    unsigned short* WVb  = (unsigned short*)(ws + 47513600);
    unsigned short* WQDb = (unsigned short*)(ws + 47644672);
    unsigned short* WKDb = (unsigned short*)(ws + 47775744);
    unsigned short* W1b  = (unsigned short*)(ws + 47906816);   // 512*768
    unsigned short* W2b  = (unsigned short*)(ws + 48693248);   // 256*512

    k_f2bf<<<256, 256, 0, stream>>>(wq,  WQb,  65536);
    k_f2bf<<<256, 256, 0, stream>>>(wk,  WKb,  65536);
    k_f2bf<<<256, 256, 0, stream>>>(wv,  WVb,  65536);
    k_f2bf<<<256, 256, 0, stream>>>(wqd, WQDb, 65536);
    k_f2bf<<<256, 256, 0, stream>>>(wkd, WKDb, 65536);
    k_f2bf<<<1536, 256, 0, stream>>>(fw1, W1b, 393216);
    k_f2bf<<<512, 256, 0, stream>>>(fw2, W2b, 131072);

    k_ln_stats<<<128, 256, 0, stream>>>(featA, STATS);
    k_transpose<1><<<dim3(64,4,2), 256, 0, stream>>>(featA, F, 768, STATS, ln_in_w, ln_in_b);
    k_transpose<0><<<dim3(64,4,2), 256, 0, stream>>>(featB, XBT, 256, nullptr, nullptr, nullptr);
    k_knn<<<NP_, 256, 0, stream>>>(xyzA, xyzB, KNNi);

    k_gemm<0><<<dim3(64,4), 256, 0, stream>>>(F,   768, WQb,  256, bq,  nullptr, QSb, 256, nullptr, nullptr);
    k_gemm<0><<<dim3(64,4), 256, 0, stream>>>(XBT, 256, WKb,  256, bk,  nullptr, KSb, 256, nullptr, nullptr);
    k_gemm<0><<<dim3(64,4), 256, 0, stream>>>(XBT, 256, WVb,  256, bv,  nullptr, VVb, 256, nullptr, nullptr);
    k_gemm<0><<<dim3(64,4), 256, 0, stream>>>(F,   768, WQDb, 256, bqd, nullptr, QDb, 256, nullptr, nullptr);
    k_gemm<0><<<dim3(64,4), 256, 0, stream>>>(XBT, 256, WKDb, 256, bkd, nullptr, KDb, 256, nullptr, nullptr);

    k_attn<<<2048, 256, 0, stream>>>(QSb, KSb, VVb, QDb, KDb, KNNi, lnsw, lnsb, lndw, lndb, F);

    k_gemm<1><<<dim3(64,8), 256, 0, stream>>>(F,  768, W1b, 768, bng, bnb, Y1, 512, nullptr, nullptr);
    k_gemm<2><<<dim3(64,4), 256, 0, stream>>>(Y1, 512, W2b, 512, fb2, nullptr, nullptr, 0, featA, out);
}

// Round 2
// 289.492 us; speedup vs baseline: 1.4265x; 1.4265x over previous
//
#include <hip/hip_runtime.h>
#include <hip/hip_bf16.h>
#include <math.h>

#define B_ 2
#define N_ 4096
#define C_ 256
#define H_ 8
#define K_ 32
#define NP_ (B_*N_)

typedef __attribute__((ext_vector_type(8))) short bf16x8;
typedef __attribute__((ext_vector_type(4))) float f32x4;
typedef __attribute__((ext_vector_type(4))) unsigned short ushort4_t;

__device__ __forceinline__ float bf2f(unsigned short v){
    union { unsigned int u; float f; } x; x.u = ((unsigned int)v) << 16; return x.f;
}
__device__ __forceinline__ unsigned short f2bf(float f){
    union { float f; unsigned int u; } x; x.f = f;
    return (unsigned short)((x.u + 0x7FFFu + ((x.u >> 16) & 1u)) >> 16);
}

// ---------------- batched weight fp32 -> bf16 into contiguous Wbase ----------------
// layout: [wq 65536][wqd 65536][wk 65536][wv 65536][wkd 65536][fw1 393216][fw2 131072]
__global__ __launch_bounds__(256) void k_cvt_all(
    const float* __restrict__ s0, const float* __restrict__ s1,
    const float* __restrict__ s2, const float* __restrict__ s3,
    const float* __restrict__ s4, const float* __restrict__ s5,
    const float* __restrict__ s6, unsigned short* __restrict__ dst)
{
    int i = blockIdx.x*256 + threadIdx.x;   // 3328*256 = 851968 exactly
    float v;
    if (i < 327680){
        int seg = i >> 16, off = i & 65535;
        const float* s = (seg==0)?s0:(seg==1)?s1:(seg==2)?s2:(seg==3)?s3:s4;
        v = s[off];
    } else if (i < 720896){
        v = s5[i - 327680];
    } else {
        v = s6[i - 720896];
    }
    dst[i] = f2bf(v);
}

// ---------------- LN stats over C for featA (B,C,N) ----------------
__global__ __launch_bounds__(256) void k_ln_stats(const float* __restrict__ fa, float* __restrict__ stats){
    __shared__ float part[2][4][64];
    const int lane = threadIdx.x & 63, wq = threadIdx.x >> 6;
    const int pbase = blockIdx.x * 64;
    const int p = pbase + lane;
    const int b = p >> 12, n = p & 4095;
    const float* base = fa + (size_t)b*C_*N_ + n;
    float s = 0.f, sq = 0.f;
    #pragma unroll 8
    for (int i = 0; i < 64; i++){
        float x = base[(size_t)(wq*64 + i)*N_];
        s += x; sq = fmaf(x, x, sq);
    }
    part[0][wq][lane] = s; part[1][wq][lane] = sq;
    __syncthreads();
    if (threadIdx.x < 64){
        int l = threadIdx.x;
        float S = part[0][0][l]+part[0][1][l]+part[0][2][l]+part[0][3][l];
        float Q = part[1][0][l]+part[1][1][l]+part[1][2][l]+part[1][3][l];
        float m = S*(1.f/256.f);
        float var = Q*(1.f/256.f) - m*m;
        stats[2*(pbase+l)]   = m;
        stats[2*(pbase+l)+1] = rsqrtf(var + 1e-5f);
    }
}

// ---------------- transpose (B,C,N)->(B,N,C) bf16, optional LN ----------------
template<int DO_LN>
__global__ __launch_bounds__(256) void k_transpose(const float* __restrict__ src,
                            unsigned short* __restrict__ dst, int dstStride,
                            const float* __restrict__ stats,
                            const float* __restrict__ lnw, const float* __restrict__ lnb){
    __shared__ float tile[64][65];
    const int b = blockIdx.z;
    const int n0 = blockIdx.x*64, c0 = blockIdx.y*64;
    const int tx = threadIdx.x & 63, ty = threadIdx.x >> 6;
    const float* sp = src + (size_t)b*C_*N_;
    #pragma unroll
    for (int i = 0; i < 16; i++){
        int cr = ty + i*4;
        tile[cr][tx] = sp[(size_t)(c0+cr)*N_ + n0 + tx];
    }
    __syncthreads();
    const int c = c0 + tx;
    #pragma unroll
    for (int i = 0; i < 16; i++){
        int nr = ty + i*4;
        int n = n0 + nr;
        float x = tile[tx][nr];
        int p = (b<<12) + n;
        if (DO_LN){
            float mean = stats[2*p], rstd = stats[2*p+1];
            x = (x - mean)*rstd*lnw[c] + lnb[c];
        }
        dst[(size_t)p*dstStride + c] = f2bf(x);
    }
}

// ---------------- KNN via radix select over u64 keys ----------------
__global__ __launch_bounds__(256) void k_knn(const float* __restrict__ xyzA, const float* __restrict__ xyzB,
                      int* __restrict__ knn){
    const int p = blockIdx.x;
    const int b = p >> 12;
    const int tid = threadIdx.x;
    const float* pa = xyzA + (size_t)p*3;
    const float ax = pa[0], ay = pa[1], az = pa[2];
    const float sa = ax*ax + ay*ay + az*az;
    const float* pb = xyzB + (size_t)b*N_*3;
    unsigned long long key[16];
    #pragma unroll
    for (int i = 0; i < 16; i++){
        int m = tid + i*256;
        float bx = pb[m*3], by = pb[m*3+1], bz = pb[m*3+2];
        float d2 = (sa + bx*bx + by*by + bz*bz) - 2.f*(ax*bx + ay*by + az*bz);
        union { float f; unsigned int u; } cv; cv.f = d2;
        unsigned int u = cv.u ^ (0x80000000u | (unsigned int)((int)cv.u >> 31));
        key[i] = (((unsigned long long)u) << 12) | (unsigned int)m;
    }
    __shared__ unsigned int hist[4][257];
    __shared__ unsigned int ctrl[4];   // [0]=selBin [1]=count_below [2]=bin count [3]=emit counter
    __shared__ unsigned long long shT;
    if (tid == 0) ctrl[3] = 0;
    const int wv = tid >> 6, ln = tid & 63;
    unsigned int r = K_;               // rank wanted (1-indexed) within current prefix class
    unsigned long long pfx = 0;
    bool done = false;
    for (int lev = 0; lev < 6 && !done; lev++){
        const int shift = (lev < 5) ? (36 - 8*lev) : 0;
        const int nb    = (lev < 5) ? 8 : 4;
        for (int z = tid; z < 4*257; z += 256) (&hist[0][0])[z] = 0u;
        __syncthreads();
        #pragma unroll
        for (int i = 0; i < 16; i++)
            if ((key[i] >> (shift + nb)) == pfx)
                atomicAdd(&hist[wv][(unsigned int)(key[i] >> shift) & ((1u<<nb)-1u)], 1u);
        __syncthreads();
        if (tid < 64){
            unsigned int v[4], tot = 0;
            #pragma unroll
            for (int j = 0; j < 4; j++){
                int bin = ln*4 + j;
                v[j] = hist[0][bin]+hist[1][bin]+hist[2][bin]+hist[3][bin];
                tot += v[j];
            }
            unsigned int sc = tot;
            #pragma unroll
            for (int off = 1; off < 64; off <<= 1){
                unsigned int o = __shfl_up(sc, off, 64);
                if (ln >= off) sc += o;
            }
            unsigned int cum = sc - tot;   // exclusive prefix over bins
            #pragma unroll
            for (int j = 0; j < 4; j++){
                unsigned int nc = cum + v[j];
                if (cum < r && nc >= r){ ctrl[0] = ln*4+j; ctrl[1] = cum; ctrl[2] = v[j]; }
                cum = nc;
            }
        }
        __syncthreads();
        unsigned int sb = ctrl[0], clt = ctrl[1], mcount = ctrl[2];
        pfx = (pfx << nb) | sb;
        r -= clt;
        if (mcount == 1u){
            #pragma unroll
            for (int i = 0; i < 16; i++)
                if ((key[i] >> shift) == pfx) shT = key[i];
            done = true;
        }
        __syncthreads();
    }
    unsigned long long T = done ? shT : pfx;
    #pragma unroll
    for (int i = 0; i < 16; i++){
        if (key[i] <= T){
            unsigned int slot = atomicAdd(&ctrl[3], 1u);
            knn[(size_t)p*K_ + slot] = (int)(key[i] & 0xFFFull);
        }
    }
}

// ---------------- generic MFMA GEMM: Y = epilogue(X(M,Kin) * W(O,Kin)^T) ----------------
// MODE 0: bias by 256-col range (e0|e1|e2) -> bf16 Y
// MODE 1: *scale(bn)+shift, relu -> bf16 Y   (e0=scale base, e1=shift)
// MODE 2: +bias(e0) + residual featA, write fp32 out transposed (B,C,N)
template<int MODE>
__global__ __launch_bounds__(256) void k_gemm(
    const unsigned short* __restrict__ X, int ldx,
    const unsigned short* __restrict__ W, int Kin,
    const float* __restrict__ e0, const float* __restrict__ e1, const float* __restrict__ e2,
    unsigned short* __restrict__ Y, int ldy,
    const float* __restrict__ resid, float* __restrict__ out)
{
    const int wid = threadIdx.x >> 6, lane = threadIdx.x & 63;
    const int lr = lane & 15, lg = lane >> 4;
    const int mw = blockIdx.x * 128 + wid * 32;
    const int cn = blockIdx.y * 64;
    f32x4 acc[2][4] = {};
    const unsigned short* xr0 = X + (size_t)(mw + lr) * ldx;
    const unsigned short* xr1 = xr0 + (size_t)16 * ldx;
    const unsigned short* wr0 = W + (size_t)(cn + lr) * Kin;
    for (int k0 = 0; k0 < Kin; k0 += 32){
        const int k = k0 + lg*8;
        bf16x8 a0 = *(const bf16x8*)(xr0 + k);
        bf16x8 a1 = *(const bf16x8*)(xr1 + k);
        #pragma unroll
        for (int ni = 0; ni < 4; ni++){
            bf16x8 bf = *(const bf16x8*)(wr0 + (size_t)ni*16*Kin + k);
            acc[0][ni] = __builtin_amdgcn_mfma_f32_16x16x32_bf16(a0, bf, acc[0][ni], 0, 0, 0);
            acc[1][ni] = __builtin_amdgcn_mfma_f32_16x16x32_bf16(a1, bf, acc[1][ni], 0, 0, 0);
        }
    }
    #pragma unroll
    for (int mi = 0; mi < 2; mi++){
        const int pbase = mw + mi*16 + lg*4;
        #pragma unroll
        for (int ni = 0; ni < 4; ni++){
            const int o = cn + ni*16 + lr;
            if (MODE == 0){
                const float* bp = (o < 256) ? e0 : ((o < 512) ? e1 : e2);
                float bias = bp[o & 255];
                #pragma unroll
                for (int r = 0; r < 4; r++)
                    Y[(size_t)(pbase + r)*ldy + o] = f2bf(acc[mi][ni][r] + bias);
            } else if (MODE == 1){
                float sc = e0[o] * 0.9999950000374997f;   // rsqrt(1+1e-5)*bn_g
                float sh = e1[o];
                #pragma unroll
                for (int r = 0; r < 4; r++){
                    float vv = fmaf(acc[mi][ni][r], sc, sh);
                    Y[(size_t)(pbase + r)*ldy + o] = f2bf(fmaxf(vv, 0.f));
                }
            } else {
                float bias = e0[o];
                const int b = pbase >> 12, nn = pbase & 4095;
                const size_t adr = ((size_t)b*C_ + o)*N_ + nn;
                f32x4 rv = *(const f32x4*)(resid + adr);
                f32x4 ov;
                #pragma unroll
                for (int r = 0; r < 4; r++) ov[r] = acc[mi][ni][r] + bias + rv[r];
                *(f32x4*)(out + adr) = ov;
            }
        }
    }
}

// ---------------- dual-path neighbor attention, one wave per point ----------------
// QQ: (8192,512) cols 0-255=q_s, 256-511=q_d ; KVD: (8192,768) cols 0-255=k_s, 256-511=v, 512-767=k_d
__global__ __launch_bounds__(256) void k_attn(
    const unsigned short* __restrict__ QQ, const unsigned short* __restrict__ KVD,
    const int* __restrict__ KNN,
    const float* __restrict__ lnsw, const float* __restrict__ lnsb,
    const float* __restrict__ lndw, const float* __restrict__ lndb,
    unsigned short* __restrict__ F)
{
    __shared__ float qs_l[4][256], qd_l[4][256];
    __shared__ float ws_l[4][8][32], wd_l[4][8][32];
    __shared__ int idx_l[4][32];
    const int wid = threadIdx.x >> 6, lane = threadIdx.x & 63;
    const int p = blockIdx.x*4 + wid;
    const int b = p >> 12;
    {
        ushort4_t qv = *(const ushort4_t*)(QQ + (size_t)p*512 + lane*4);
        ushort4_t dv = *(const ushort4_t*)(QQ + (size_t)p*512 + 256 + lane*4);
        #pragma unroll
        for (int j = 0; j < 4; j++){
            qs_l[wid][lane*4+j] = bf2f(qv[j]);
            qd_l[wid][lane*4+j] = bf2f(dv[j]);
        }
        if (lane < 32) idx_l[wid][lane] = KNN[(size_t)p*K_ + lane];
    }
    __syncthreads();
    const int kk = lane & 31, hg = lane >> 5;
    {
        const int nbr = idx_l[wid][kk];
        const unsigned short* base = KVD + ((size_t)(b<<12) + nbr)*768;
        const unsigned short* krow = base;
        const unsigned short* drow = base + 512;
        #pragma unroll
        for (int j = 0; j < 4; j++){
            const int h = hg*4 + j;
            const float* qs_h = &qs_l[wid][h*32];
            const float* qd_h = &qd_l[wid][h*32];
            const bf16x8* kr = (const bf16x8*)(krow + h*32);
            const bf16x8* dr = (const bf16x8*)(drow + h*32);
            float s = 0.f, dd = 0.f;
            #pragma unroll
            for (int c8 = 0; c8 < 4; c8++){
                bf16x8 kv = kr[c8], dvv = dr[c8];
                #pragma unroll
                for (int e = 0; e < 8; e++){
                    int d = c8*8 + e;
                    s = fmaf(qs_h[d], bf2f((unsigned short)kv[e]), s);
                    float df = qd_h[d] - bf2f((unsigned short)dvv[e]);
                    dd = fmaf(df, df, dd);
                }
            }
            float sim = s * 0.17677669529663687f;   // 1/sqrt(32)
            float dist = sqrtf(dd);
            float m1 = sim, m2 = dist;
            #pragma unroll
            for (int off = 1; off < 32; off <<= 1){
                m1 = fmaxf(m1, __shfl_xor(m1, off, 64));
                m2 = fmaxf(m2, __shfl_xor(m2, off, 64));
            }
            float e1v = __expf(sim - m1);
            float e2v = __expf(dist - m2);
            float s1 = e1v, s2 = e2v;
            #pragma unroll
            for (int off = 1; off < 32; off <<= 1){
                s1 += __shfl_xor(s1, off, 64);
                s2 += __shfl_xor(s2, off, 64);
            }
            ws_l[wid][h][kk] = e1v / s1;
            wd_l[wid][h][kk] = e2v / s2;
        }
    }
    __syncthreads();
    const int d = kk;
    float cs[4] = {0,0,0,0}, cd[4] = {0,0,0,0};
    for (int t = 0; t < 32; t++){
        const int nbr = idx_l[wid][t];
        const unsigned short* vrow = KVD + ((size_t)(b<<12) + nbr)*768 + 256;
        #pragma unroll
        for (int j = 0; j < 4; j++){
            const int h = hg*4 + j;
            float vf = bf2f(vrow[h*32 + d]);
            cs[j] = fmaf(ws_l[wid][h][t], vf, cs[j]);
            cd[j] = fmaf(wd_l[wid][h][t], vf, cd[j]);
        }
    }
    float s1 = 0.f, q1 = 0.f, s2 = 0.f, q2 = 0.f;
    #pragma unroll
    for (int j = 0; j < 4; j++){
        s1 += cs[j]; q1 = fmaf(cs[j], cs[j], q1);
        s2 += cd[j]; q2 = fmaf(cd[j], cd[j], q2);
    }
    #pragma unroll
    for (int off = 1; off < 64; off <<= 1){
        s1 += __shfl_xor(s1, off, 64); q1 += __shfl_xor(q1, off, 64);
        s2 += __shfl_xor(s2, off, 64); q2 += __shfl_xor(q2, off, 64);
    }
    float m1 = s1*(1.f/256.f), m2 = s2*(1.f/256.f);
    float r1 = rsqrtf(q1*(1.f/256.f) - m1*m1 + 1e-5f);
    float r2 = rsqrtf(q2*(1.f/256.f) - m2*m2 + 1e-5f);
    unsigned short* frow = F + (size_t)p*768;
    #pragma unroll
    for (int j = 0; j < 4; j++){
        int c = (hg*4 + j)*32 + d;
        frow[256 + c] = f2bf((cs[j]-m1)*r1*lnsw[c] + lnsb[c]);
        frow[512 + c] = f2bf((cd[j]-m2)*r2*lndw[c] + lndb[c]);
    }
}

extern "C" void kernel_launch(void* const* d_in, const int* in_sizes, int n_in,
                              void* d_out, int out_size, void* d_ws, size_t ws_size,
                              hipStream_t stream)
{
    const float* xyzA   = (const float*)d_in[0];
    const float* xyzB   = (const float*)d_in[1];
    const float* featA  = (const float*)d_in[2];
    const float* featB  = (const float*)d_in[3];
    const float* ln_in_w= (const float*)d_in[4];
    const float* ln_in_b= (const float*)d_in[5];
    const float* wq  = (const float*)d_in[6];
    const float* bq  = (const float*)d_in[7];
    const float* wk  = (const float*)d_in[8];
    const float* bk  = (const float*)d_in[9];
    const float* wv  = (const float*)d_in[10];
    const float* bv  = (const float*)d_in[11];
    const float* wqd = (const float*)d_in[12];
    const float* bqd = (const float*)d_in[13];
    const float* wkd = (const float*)d_in[14];
    const float* bkd = (const float*)d_in[15];
    const float* lnsw = (const float*)d_in[16];
    const float* lnsb = (const float*)d_in[17];
    const float* lndw = (const float*)d_in[18];
    const float* lndb = (const float*)d_in[19];
    const float* fw1 = (const float*)d_in[20];
    const float* bng = (const float*)d_in[21];
    const float* bnb = (const float*)d_in[22];
    const float* fw2 = (const float*)d_in[23];
    const float* fb2 = (const float*)d_in[24];
    float* out = (float*)d_out;
    char* ws = (char*)d_ws;

    unsigned short* F    = (unsigned short*)(ws + 0);          // 8192*768 bf16
    unsigned short* XBT  = (unsigned short*)(ws + 12582912);   // 8192*256
    unsigned short* QQ   = (unsigned short*)(ws + 16777216);   // 8192*512
    unsigned short* KVD  = (unsigned short*)(ws + 25165824);   // 8192*768
    unsigned short* Y1   = (unsigned short*)(ws + 37748736);   // 8192*512
    int*            KNNi = (int*)(ws + 46137344);              // 8192*32
    float*          STATS= (float*)(ws + 47185920);            // 8192*2
    unsigned short* Wb   = (unsigned short*)(ws + 47251456);   // 851968 bf16
    unsigned short* WQcat = Wb;                // 512x256
    unsigned short* WKVD  = Wb + 131072;       // 768x256
    unsigned short* W1b   = Wb + 327680;       // 512x768
    unsigned short* W2b   = Wb + 720896;       // 256x512

    k_cvt_all<<<3328, 256, 0, stream>>>(wq, wqd, wk, wv, wkd, fw1, fw2, Wb);

    k_ln_stats<<<128, 256, 0, stream>>>(featA, STATS);
    k_transpose<1><<<dim3(64,4,2), 256, 0, stream>>>(featA, F, 768, STATS, ln_in_w, ln_in_b);
    k_transpose<0><<<dim3(64,4,2), 256, 0, stream>>>(featB, XBT, 256, nullptr, nullptr, nullptr);
    k_knn<<<NP_, 256, 0, stream>>>(xyzA, xyzB, KNNi);

    k_gemm<0><<<dim3(64,8), 256, 0, stream>>>(F,   768, WQcat, 256, bq, bqd, nullptr, QQ, 512, nullptr, nullptr);
    k_gemm<0><<<dim3(64,12), 256, 0, stream>>>(XBT, 256, WKVD, 256, bk, bv, bkd, KVD, 768, nullptr, nullptr);

    k_attn<<<2048, 256, 0, stream>>>(QQ, KVD, KNNi, lnsw, lnsb, lndw, lndb, F);

    k_gemm<1><<<dim3(64,8), 256, 0, stream>>>(F,  768, W1b, 768, bng, bnb, nullptr, Y1, 512, nullptr, nullptr);
    k_gemm<2><<<dim3(64,4), 256, 0, stream>>>(Y1, 512, W2b, 512, fb2, nullptr, nullptr, nullptr, 0, featA, out);
}